// Round 2
// baseline (217.698 us; speedup 1.0000x reference)
//
#include <hip/hip_runtime.h>
#include <math.h>

#define IMG 512
#define TS  32      // square output tile
#define RAD 5       // (11-1)/2
#define IT  42      // input tile = TS + 10
#define IWP 44      // padded input row stride (floats); 176B rows, 16B-aligned
#define HWP 36      // padded h-field row stride; 144B rows, 16B-aligned
#define NG  (IT * (TS / 4))   // 42*8 = 336 horizontal work groups

struct W11 { float w[11]; };

__device__ __forceinline__ unsigned omap(float f) {
  unsigned b = __float_as_uint(f);
  return (b & 0x80000000u) ? ~b : (b | 0x80000000u);
}
__device__ __forceinline__ float ounmap(unsigned u) {
  return __uint_as_float((u & 0x80000000u) ? (u ^ 0x80000000u) : ~u);
}

__global__ void init_mm(unsigned* ws) {
  if (threadIdx.x == 0) { ws[0] = 0u; ws[1] = 0xFFFFFFFFu; }
}

__global__ __launch_bounds__(256) void minmax_k(const float4* __restrict__ img,
                                                int n4, unsigned* ws) {
  unsigned mx = 0u, mn = 0xFFFFFFFFu;
  int stride = gridDim.x * blockDim.x;
  for (int i = blockIdx.x * blockDim.x + threadIdx.x; i < n4; i += stride) {
    float4 v = img[i];
    unsigned a = omap(v.x), b = omap(v.y), c = omap(v.z), d = omap(v.w);
    mx = max(mx, max(max(a, b), max(c, d)));
    mn = min(mn, min(min(a, b), min(c, d)));
  }
  #pragma unroll
  for (int off = 32; off > 0; off >>= 1) {
    mx = max(mx, __shfl_down(mx, off));
    mn = min(mn, __shfl_down(mn, off));
  }
  __shared__ unsigned smx[4], smn[4];
  int lane = threadIdx.x & 63, wv = threadIdx.x >> 6;
  if (lane == 0) { smx[wv] = mx; smn[wv] = mn; }
  __syncthreads();
  if (threadIdx.x == 0) {
    mx = max(max(smx[0], smx[1]), max(smx[2], smx[3]));
    mn = min(min(smn[0], smn[1]), min(smn[2], smn[3]));
    atomicMax(&ws[0], mx);
    atomicMin(&ws[1], mn);
  }
}

// Fused SSIM: stage -> h-conv (held in regs) -> [LDS aliased] h-fields -> v-conv -> formula
__global__ __launch_bounds__(256, 4) void ssim_k(const float* __restrict__ img1,
                                                 const float* __restrict__ img2,
                                                 float* __restrict__ out,
                                                 const unsigned* __restrict__ ws,
                                                 W11 wv) {
  // Aliased LDS: staging buffers are dead once h-conv results sit in registers.
  // union => 30,240 B instead of 45 KB => 5 blocks/CU by LDS (vs 3 before).
  __shared__ union U {
    struct { float in1[IT][IWP]; float in2[IT][IWP]; } s;
    float H[5][IT][HWP];   // h-conv of: x1, x2, x1^2, x2^2, x1*x2
  } u;

  const int tid = threadIdx.x;
  const int bx = blockIdx.x, by = blockIdx.y, n = blockIdx.z;
  const float* p1 = img1 + (size_t)n * IMG * IMG;
  const float* p2 = img2 + (size_t)n * IMG * IMG;
  const int x0 = bx * TS - RAD;
  const int y0 = by * TS - RAD;

  // ---- stage (interior blocks skip bounds checks; block-uniform branch) ----
  const bool interior = (bx > 0) & (bx < IMG / TS - 1) & (by > 0) & (by < IMG / TS - 1);
  if (interior) {
    for (int idx = tid; idx < IT * IT; idx += 256) {
      int r = idx / IT, c = idx - r * IT;
      int off = (y0 + r) * IMG + (x0 + c);
      u.s.in1[r][c] = p1[off];
      u.s.in2[r][c] = p2[off];
    }
  } else {
    for (int idx = tid; idx < IT * IT; idx += 256) {
      int r = idx / IT, c = idx - r * IT;
      int gx = x0 + c, gy = y0 + r;
      bool ok = (gx >= 0) & (gx < IMG) & (gy >= 0) & (gy < IMG);
      int off = gy * IMG + gx;
      u.s.in1[r][c] = ok ? p1[off] : 0.f;
      u.s.in2[r][c] = ok ? p2[off] : 0.f;
    }
  }
  __syncthreads();

  // ---- horizontal pass: results held in registers across the aliasing barrier ----
  float A[2][5][4];   // [iter][field][point]
  #pragma unroll
  for (int it = 0; it < 2; ++it) {
    int g = tid + it * 256;
    if (g < NG) {
      int r = g >> 3;            // row 0..41
      int xg = (g & 7) << 2;     // first of 4 h-field columns (0..28)
      float a[16], b[16];
      *(float4*)&a[0]  = *(const float4*)&u.s.in1[r][xg + 0];
      *(float4*)&a[4]  = *(const float4*)&u.s.in1[r][xg + 4];
      *(float4*)&a[8]  = *(const float4*)&u.s.in1[r][xg + 8];
      *(float4*)&a[12] = *(const float4*)&u.s.in1[r][xg + 12];
      *(float4*)&b[0]  = *(const float4*)&u.s.in2[r][xg + 0];
      *(float4*)&b[4]  = *(const float4*)&u.s.in2[r][xg + 4];
      *(float4*)&b[8]  = *(const float4*)&u.s.in2[r][xg + 8];
      *(float4*)&b[12] = *(const float4*)&u.s.in2[r][xg + 12];

      float a2[14], b2[14], ab[14];
      #pragma unroll
      for (int t = 0; t < 14; ++t) { a2[t] = a[t]*a[t]; b2[t] = b[t]*b[t]; ab[t] = a[t]*b[t]; }

      #pragma unroll
      for (int f = 0; f < 5; ++f)
        #pragma unroll
        for (int j = 0; j < 4; ++j) A[it][f][j] = 0.f;

      #pragma unroll
      for (int k = 0; k < 11; ++k) {
        float wk = wv.w[k];
        #pragma unroll
        for (int j = 0; j < 4; ++j) {
          A[it][0][j] += wk * a[j + k];
          A[it][1][j] += wk * b[j + k];
          A[it][2][j] += wk * a2[j + k];
          A[it][3][j] += wk * b2[j + k];
          A[it][4][j] += wk * ab[j + k];
        }
      }
    }
  }
  __syncthreads();   // all reads of u.s.* complete; safe to overwrite via u.H

  #pragma unroll
  for (int it = 0; it < 2; ++it) {
    int g = tid + it * 256;
    if (g < NG) {
      int r = g >> 3;
      int xg = (g & 7) << 2;
      #pragma unroll
      for (int f = 0; f < 5; ++f)
        *(float4*)&u.H[f][r][xg] =
            make_float4(A[it][f][0], A[it][f][1], A[it][f][2], A[it][f][3]);
    }
  }
  __syncthreads();

  // ---- C1/C2 from global min/max ----
  float L = ounmap(ws[0]) - ounmap(ws[1]);
  if (L == 0.f) L = 5.f;
  float C1 = 0.01f * L; C1 *= C1;
  float C2 = 0.03f * L; C2 *= C2;

  // ---- vertical pass: thread = (col x, 4 consecutive rows) ----
  const int x = tid & 31;
  const int yb = (tid >> 5) << 2;
  float acc[5][4];
  #pragma unroll
  for (int f = 0; f < 5; ++f)
    #pragma unroll
    for (int j = 0; j < 4; ++j) acc[f][j] = 0.f;

  #pragma unroll
  for (int f = 0; f < 5; ++f) {
    float v[14];
    #pragma unroll
    for (int i = 0; i < 14; ++i) v[i] = u.H[f][yb + i][x];
    #pragma unroll
    for (int k = 0; k < 11; ++k) {
      float wk = wv.w[k];
      #pragma unroll
      for (int j = 0; j < 4; ++j) acc[f][j] += wk * v[j + k];
    }
  }

  #pragma unroll
  for (int j = 0; j < 4; ++j) {
    float mu1 = acc[0][j], mu2 = acc[1][j];
    float mu1s = mu1 * mu1, mu2s = mu2 * mu2, mu12 = mu1 * mu2;
    float s1 = acc[2][j] - mu1s, s2 = acc[3][j] - mu2s, s12 = acc[4][j] - mu12;
    float num = (2.f * mu12 + C1) * (2.f * s12 + C2);
    float den = (mu1s + mu2s + C1) * (s1 + s2 + C2);
    int gy = by * TS + yb + j, gx = bx * TS + x;
    out[(size_t)n * IMG * IMG + (size_t)gy * IMG + gx] = num / den;
  }
}

extern "C" void kernel_launch(void* const* d_in, const int* in_sizes, int n_in,
                              void* d_out, int out_size, void* d_ws, size_t ws_size,
                              hipStream_t stream) {
  const float* img1 = (const float*)d_in[0];
  const float* img2 = (const float*)d_in[1];
  float* out = (float*)d_out;
  unsigned* ws = (unsigned*)d_ws;
  int n = in_sizes[0];             // 32*1*512*512
  int batch = n / (IMG * IMG);     // 32

  // Gaussian window, center at ws/2 = 5.5 (asymmetric!), normalized — matches reference
  W11 wv;
  double g[11], s = 0.0;
  for (int i = 0; i < 11; ++i) { double d = i - 5.5; g[i] = exp(-(d * d) / 4.5); s += g[i]; }
  for (int i = 0; i < 11; ++i) wv.w[i] = (float)(g[i] / s);

  init_mm<<<1, 64, 0, stream>>>(ws);
  minmax_k<<<2048, 256, 0, stream>>>((const float4*)img1, n / 4, ws);
  dim3 grid(IMG / TS, IMG / TS, batch);
  ssim_k<<<grid, 256, 0, stream>>>(img1, img2, out, ws, wv);
}

// Round 3
// 200.326 us; speedup vs baseline: 1.0867x; 1.0867x over previous
//
#include <hip/hip_runtime.h>
#include <math.h>

#define IMG 512
#define TW 64      // output tile width
#define TH 16      // output tile height
#define RAD 5
#define IW 74      // input tile width  (TW+10)
#define IH 26      // input tile height (TH+10)
#define IWP 76     // padded input row stride (16B-aligned)
#define HWP 68     // padded h-field row stride (16B-aligned)
#define NG (IH * (TW / 4))   // 26*16 = 416 horizontal tasks

struct W11 { float w[11]; };

__device__ __forceinline__ unsigned omap(float f) {
  unsigned b = __float_as_uint(f);
  return (b & 0x80000000u) ? ~b : (b | 0x80000000u);
}
__device__ __forceinline__ float ounmap(unsigned u) {
  return __uint_as_float((u & 0x80000000u) ? (u ^ 0x80000000u) : ~u);
}

__global__ void init_mm(unsigned* ws) {
  if (threadIdx.x == 0) { ws[0] = 0u; ws[1] = 0xFFFFFFFFu; }
}

// 512 blocks -> only 1024 same-address atomics (was 4096: ~100us of serialization)
__global__ __launch_bounds__(256) void minmax_k(const float4* __restrict__ img,
                                                int n4, unsigned* ws) {
  unsigned mx = 0u, mn = 0xFFFFFFFFu;
  int stride = gridDim.x * blockDim.x;
  for (int i = blockIdx.x * blockDim.x + threadIdx.x; i < n4; i += stride) {
    float4 v = img[i];
    unsigned a = omap(v.x), b = omap(v.y), c = omap(v.z), d = omap(v.w);
    mx = max(mx, max(max(a, b), max(c, d)));
    mn = min(mn, min(min(a, b), min(c, d)));
  }
  #pragma unroll
  for (int off = 32; off > 0; off >>= 1) {
    mx = max(mx, __shfl_down(mx, off));
    mn = min(mn, __shfl_down(mn, off));
  }
  __shared__ unsigned smx[4], smn[4];
  int lane = threadIdx.x & 63, wv = threadIdx.x >> 6;
  if (lane == 0) { smx[wv] = mx; smn[wv] = mn; }
  __syncthreads();
  if (threadIdx.x == 0) {
    mx = max(max(smx[0], smx[1]), max(smx[2], smx[3]));
    mn = min(min(smn[0], smn[1]), min(smn[2], smn[3]));
    atomicMax(&ws[0], mx);
    atomicMin(&ws[1], mn);
  }
}

// Fused SSIM, 64x16 tile (R1's low-conflict/low-fetch shape) + LDS union aliasing
__global__ __launch_bounds__(256, 4) void ssim_k(const float* __restrict__ img1,
                                                 const float* __restrict__ img2,
                                                 float* __restrict__ out,
                                                 const unsigned* __restrict__ ws,
                                                 W11 wv) {
  // staging buffers die once h-conv results sit in registers -> alias with H
  // union = max(15.8KB, 35.4KB) = 35.4KB -> 4 blocks/CU (vs 3 at 51.2KB)
  __shared__ union U {
    struct { float in1[IH][IWP]; float in2[IH][IWP]; } s;
    float H[5][IH][HWP];   // h-conv of: x1, x2, x1^2, x2^2, x1*x2
  } u;

  const int tid = threadIdx.x;
  const int bx = blockIdx.x, by = blockIdx.y, n = blockIdx.z;
  const float* p1 = img1 + (size_t)n * IMG * IMG;
  const float* p2 = img2 + (size_t)n * IMG * IMG;
  const int x0 = bx * TW - RAD;
  const int y0 = by * TH - RAD;

  // ---- stage (interior blocks skip bounds checks) ----
  const bool interior = (bx > 0) & (bx < IMG / TW - 1) & (by > 0) & (by < IMG / TH - 1);
  if (interior) {
    for (int idx = tid; idx < IH * IW; idx += 256) {
      int r = idx / IW, c = idx - r * IW;
      int off = (y0 + r) * IMG + (x0 + c);
      u.s.in1[r][c] = p1[off];
      u.s.in2[r][c] = p2[off];
    }
  } else {
    for (int idx = tid; idx < IH * IW; idx += 256) {
      int r = idx / IW, c = idx - r * IW;
      int gx = x0 + c, gy = y0 + r;
      bool ok = (gx >= 0) & (gx < IMG) & (gy >= 0) & (gy < IMG);
      int off = gy * IMG + gx;
      u.s.in1[r][c] = ok ? p1[off] : 0.f;
      u.s.in2[r][c] = ok ? p2[off] : 0.f;
    }
  }
  __syncthreads();

  // ---- horizontal pass: results held in registers across the aliasing barrier ----
  float A[2][5][4];
  #pragma unroll
  for (int it = 0; it < 2; ++it) {
    int g = tid + it * 256;
    if (g < NG) {
      int r = g >> 4;            // row 0..25 (16 lanes per row -> clean banks)
      int xg = (g & 15) << 2;    // first of 4 h-field columns (0..60)
      float a[16], b[16];
      *(float4*)&a[0]  = *(const float4*)&u.s.in1[r][xg + 0];
      *(float4*)&a[4]  = *(const float4*)&u.s.in1[r][xg + 4];
      *(float4*)&a[8]  = *(const float4*)&u.s.in1[r][xg + 8];
      *(float4*)&a[12] = *(const float4*)&u.s.in1[r][xg + 12];
      *(float4*)&b[0]  = *(const float4*)&u.s.in2[r][xg + 0];
      *(float4*)&b[4]  = *(const float4*)&u.s.in2[r][xg + 4];
      *(float4*)&b[8]  = *(const float4*)&u.s.in2[r][xg + 8];
      *(float4*)&b[12] = *(const float4*)&u.s.in2[r][xg + 12];

      float a2[14], b2[14], ab[14];
      #pragma unroll
      for (int t = 0; t < 14; ++t) { a2[t] = a[t]*a[t]; b2[t] = b[t]*b[t]; ab[t] = a[t]*b[t]; }

      #pragma unroll
      for (int f = 0; f < 5; ++f)
        #pragma unroll
        for (int j = 0; j < 4; ++j) A[it][f][j] = 0.f;

      #pragma unroll
      for (int k = 0; k < 11; ++k) {
        float wk = wv.w[k];
        #pragma unroll
        for (int j = 0; j < 4; ++j) {
          A[it][0][j] += wk * a[j + k];
          A[it][1][j] += wk * b[j + k];
          A[it][2][j] += wk * a2[j + k];
          A[it][3][j] += wk * b2[j + k];
          A[it][4][j] += wk * ab[j + k];
        }
      }
    }
  }
  __syncthreads();   // all staging reads done; safe to overwrite via u.H

  #pragma unroll
  for (int it = 0; it < 2; ++it) {
    int g = tid + it * 256;
    if (g < NG) {
      int r = g >> 4;
      int xg = (g & 15) << 2;
      #pragma unroll
      for (int f = 0; f < 5; ++f)
        *(float4*)&u.H[f][r][xg] =
            make_float4(A[it][f][0], A[it][f][1], A[it][f][2], A[it][f][3]);
    }
  }
  __syncthreads();

  // ---- C1/C2 from global min/max ----
  float L = ounmap(ws[0]) - ounmap(ws[1]);
  if (L == 0.f) L = 5.f;
  float C1 = 0.01f * L; C1 *= C1;
  float C2 = 0.03f * L; C2 *= C2;

  // ---- vertical pass: 128 threads, each = (1 col x, 8 rows) ----
  // reads per output: 5*18/8 = 11.25 b32 (was 17.5); full-wave column reads
  // hit banks (x + 4*row) % 32 with all 64 lanes same row -> conflict-free.
  if (tid < 128) {
    const int x = tid & 63;
    const int yb = (tid >> 6) << 3;   // 0 or 8
    float acc[5][8];
    #pragma unroll
    for (int f = 0; f < 5; ++f)
      #pragma unroll
      for (int j = 0; j < 8; ++j) acc[f][j] = 0.f;

    #pragma unroll
    for (int f = 0; f < 5; ++f) {
      float v[18];
      #pragma unroll
      for (int i = 0; i < 18; ++i) v[i] = u.H[f][yb + i][x];
      #pragma unroll
      for (int k = 0; k < 11; ++k) {
        float wk = wv.w[k];
        #pragma unroll
        for (int j = 0; j < 8; ++j) acc[f][j] += wk * v[j + k];
      }
    }

    #pragma unroll
    for (int j = 0; j < 8; ++j) {
      float mu1 = acc[0][j], mu2 = acc[1][j];
      float mu1s = mu1 * mu1, mu2s = mu2 * mu2, mu12 = mu1 * mu2;
      float s1 = acc[2][j] - mu1s, s2 = acc[3][j] - mu2s, s12 = acc[4][j] - mu12;
      float num = (2.f * mu12 + C1) * (2.f * s12 + C2);
      float den = (mu1s + mu2s + C1) * (s1 + s2 + C2);
      int gy = by * TH + yb + j, gx = bx * TW + x;
      out[(size_t)n * IMG * IMG + (size_t)gy * IMG + gx] = num / den;
    }
  }
}

extern "C" void kernel_launch(void* const* d_in, const int* in_sizes, int n_in,
                              void* d_out, int out_size, void* d_ws, size_t ws_size,
                              hipStream_t stream) {
  const float* img1 = (const float*)d_in[0];
  const float* img2 = (const float*)d_in[1];
  float* out = (float*)d_out;
  unsigned* ws = (unsigned*)d_ws;
  int n = in_sizes[0];             // 32*1*512*512
  int batch = n / (IMG * IMG);     // 32

  // Gaussian window, center at ws/2 = 5.5 (asymmetric!), normalized
  W11 wv;
  double g[11], s = 0.0;
  for (int i = 0; i < 11; ++i) { double d = i - 5.5; g[i] = exp(-(d * d) / 4.5); s += g[i]; }
  for (int i = 0; i < 11; ++i) wv.w[i] = (float)(g[i] / s);

  init_mm<<<1, 64, 0, stream>>>(ws);
  minmax_k<<<512, 256, 0, stream>>>((const float4*)img1, n / 4, ws);
  dim3 grid(IMG / TW, IMG / TH, batch);
  ssim_k<<<grid, 256, 0, stream>>>(img1, img2, out, ws, wv);
}

// Round 4
// 189.313 us; speedup vs baseline: 1.1499x; 1.0582x over previous
//
#include <hip/hip_runtime.h>
#include <math.h>

#define IMG 512
#define TW 64      // output tile width
#define TH 16      // output tile height
#define RAD 5
#define IW 74      // input tile width  (TW+10)
#define IH 26      // input tile height (TH+10)
#define IWP 76     // padded input row stride (16B-aligned)
#define HWP 68     // padded h-field row stride (16B-aligned)
#define NG (IH * (TW / 4))   // 26*16 = 416 horizontal tasks
#define MMB 256    // minmax stage-1 blocks

struct W11 { float w[11]; };

__device__ __forceinline__ unsigned omap(float f) {
  unsigned b = __float_as_uint(f);
  return (b & 0x80000000u) ? ~b : (b | 0x80000000u);
}
__device__ __forceinline__ float ounmap(unsigned u) {
  return __uint_as_float((u & 0x80000000u) ? (u ^ 0x80000000u) : ~u);
}

// Stage 1: per-block partial min/max -> plain stores to disjoint slots (NO atomics;
// same-address device atomics measured ~90us for this reduction in R1-R3).
__global__ __launch_bounds__(256) void minmax_part(const float4* __restrict__ img,
                                                   int n4, unsigned* __restrict__ part) {
  unsigned mx = 0u, mn = 0xFFFFFFFFu;
  int stride = gridDim.x * blockDim.x;
  for (int i = blockIdx.x * blockDim.x + threadIdx.x; i < n4; i += stride) {
    float4 v = img[i];
    unsigned a = omap(v.x), b = omap(v.y), c = omap(v.z), d = omap(v.w);
    mx = max(mx, max(max(a, b), max(c, d)));
    mn = min(mn, min(min(a, b), min(c, d)));
  }
  #pragma unroll
  for (int off = 32; off > 0; off >>= 1) {
    mx = max(mx, __shfl_down(mx, off));
    mn = min(mn, __shfl_down(mn, off));
  }
  __shared__ unsigned smx[4], smn[4];
  int lane = threadIdx.x & 63, wv = threadIdx.x >> 6;
  if (lane == 0) { smx[wv] = mx; smn[wv] = mn; }
  __syncthreads();
  if (threadIdx.x == 0) {
    mx = max(max(smx[0], smx[1]), max(smx[2], smx[3]));
    mn = min(min(smn[0], smn[1]), min(smn[2], smn[3]));
    part[2 * blockIdx.x]     = mx;
    part[2 * blockIdx.x + 1] = mn;
  }
}

// Stage 2: one block folds the MMB partial pairs into ws[0]=max, ws[1]=min.
__global__ __launch_bounds__(256) void minmax_final(const unsigned* __restrict__ part,
                                                    unsigned* __restrict__ ws) {
  unsigned mx = 0u, mn = 0xFFFFFFFFu;
  for (int i = threadIdx.x; i < MMB; i += 256) {
    mx = max(mx, part[2 * i]);
    mn = min(mn, part[2 * i + 1]);
  }
  #pragma unroll
  for (int off = 32; off > 0; off >>= 1) {
    mx = max(mx, __shfl_down(mx, off));
    mn = min(mn, __shfl_down(mn, off));
  }
  __shared__ unsigned smx[4], smn[4];
  int lane = threadIdx.x & 63, wv = threadIdx.x >> 6;
  if (lane == 0) { smx[wv] = mx; smn[wv] = mn; }
  __syncthreads();
  if (threadIdx.x == 0) {
    ws[0] = max(max(smx[0], smx[1]), max(smx[2], smx[3]));
    ws[1] = min(min(smn[0], smn[1]), min(smn[2], smn[3]));
  }
}

// Fused SSIM, 64x16 tile, LDS union aliasing, v-pass = R1's 256-thread pattern
__global__ __launch_bounds__(256, 4) void ssim_k(const float* __restrict__ img1,
                                                 const float* __restrict__ img2,
                                                 float* __restrict__ out,
                                                 const unsigned* __restrict__ ws,
                                                 W11 wv) {
  // staging buffers die once h-conv results sit in registers -> alias with H
  // union = max(15.8KB, 35.4KB) = 35.4KB -> 4 blocks/CU
  __shared__ union U {
    struct { float in1[IH][IWP]; float in2[IH][IWP]; } s;
    float H[5][IH][HWP];   // h-conv of: x1, x2, x1^2, x2^2, x1*x2
  } u;

  const int tid = threadIdx.x;
  const int bx = blockIdx.x, by = blockIdx.y, n = blockIdx.z;
  const float* p1 = img1 + (size_t)n * IMG * IMG;
  const float* p2 = img2 + (size_t)n * IMG * IMG;
  const int x0 = bx * TW - RAD;
  const int y0 = by * TH - RAD;

  // ---- stage (interior blocks skip bounds checks) ----
  const bool interior = (bx > 0) & (bx < IMG / TW - 1) & (by > 0) & (by < IMG / TH - 1);
  if (interior) {
    for (int idx = tid; idx < IH * IW; idx += 256) {
      int r = idx / IW, c = idx - r * IW;
      int off = (y0 + r) * IMG + (x0 + c);
      u.s.in1[r][c] = p1[off];
      u.s.in2[r][c] = p2[off];
    }
  } else {
    for (int idx = tid; idx < IH * IW; idx += 256) {
      int r = idx / IW, c = idx - r * IW;
      int gx = x0 + c, gy = y0 + r;
      bool ok = (gx >= 0) & (gx < IMG) & (gy >= 0) & (gy < IMG);
      int off = gy * IMG + gx;
      u.s.in1[r][c] = ok ? p1[off] : 0.f;
      u.s.in2[r][c] = ok ? p2[off] : 0.f;
    }
  }
  __syncthreads();

  // ---- horizontal pass: results held in registers across the aliasing barrier ----
  float A[2][5][4];
  #pragma unroll
  for (int it = 0; it < 2; ++it) {
    int g = tid + it * 256;
    if (g < NG) {
      int r = g >> 4;            // row 0..25
      int xg = (g & 15) << 2;    // first of 4 h-field columns (0..60)
      float a[16], b[16];
      *(float4*)&a[0]  = *(const float4*)&u.s.in1[r][xg + 0];
      *(float4*)&a[4]  = *(const float4*)&u.s.in1[r][xg + 4];
      *(float4*)&a[8]  = *(const float4*)&u.s.in1[r][xg + 8];
      *(float4*)&a[12] = *(const float4*)&u.s.in1[r][xg + 12];
      *(float4*)&b[0]  = *(const float4*)&u.s.in2[r][xg + 0];
      *(float4*)&b[4]  = *(const float4*)&u.s.in2[r][xg + 4];
      *(float4*)&b[8]  = *(const float4*)&u.s.in2[r][xg + 8];
      *(float4*)&b[12] = *(const float4*)&u.s.in2[r][xg + 12];

      float a2[14], b2[14], ab[14];
      #pragma unroll
      for (int t = 0; t < 14; ++t) { a2[t] = a[t]*a[t]; b2[t] = b[t]*b[t]; ab[t] = a[t]*b[t]; }

      #pragma unroll
      for (int f = 0; f < 5; ++f)
        #pragma unroll
        for (int j = 0; j < 4; ++j) A[it][f][j] = 0.f;

      #pragma unroll
      for (int k = 0; k < 11; ++k) {
        float wk = wv.w[k];
        #pragma unroll
        for (int j = 0; j < 4; ++j) {
          A[it][0][j] += wk * a[j + k];
          A[it][1][j] += wk * b[j + k];
          A[it][2][j] += wk * a2[j + k];
          A[it][3][j] += wk * b2[j + k];
          A[it][4][j] += wk * ab[j + k];
        }
      }
    }
  }
  __syncthreads();   // all staging reads done; safe to overwrite via u.H

  #pragma unroll
  for (int it = 0; it < 2; ++it) {
    int g = tid + it * 256;
    if (g < NG) {
      int r = g >> 4;
      int xg = (g & 15) << 2;
      #pragma unroll
      for (int f = 0; f < 5; ++f)
        *(float4*)&u.H[f][r][xg] =
            make_float4(A[it][f][0], A[it][f][1], A[it][f][2], A[it][f][3]);
    }
  }
  __syncthreads();

  // ---- C1/C2 from global min/max ----
  float L = ounmap(ws[0]) - ounmap(ws[1]);
  if (L == 0.f) L = 5.f;
  float C1 = 0.01f * L; C1 *= C1;
  float C2 = 0.03f * L; C2 *= C2;

  // ---- vertical pass: 256 threads, each = (1 col x, 4 rows); full-wave
  // consecutive-column reads = 2 lanes/bank = conflict-free ----
  const int x = tid & 63;
  const int yb = (tid >> 6) << 2;
  float acc[5][4];
  #pragma unroll
  for (int f = 0; f < 5; ++f)
    #pragma unroll
    for (int j = 0; j < 4; ++j) acc[f][j] = 0.f;

  #pragma unroll
  for (int f = 0; f < 5; ++f) {
    float v[14];
    #pragma unroll
    for (int i = 0; i < 14; ++i) v[i] = u.H[f][yb + i][x];
    #pragma unroll
    for (int k = 0; k < 11; ++k) {
      float wk = wv.w[k];
      #pragma unroll
      for (int j = 0; j < 4; ++j) acc[f][j] += wk * v[j + k];
    }
  }

  #pragma unroll
  for (int j = 0; j < 4; ++j) {
    float mu1 = acc[0][j], mu2 = acc[1][j];
    float mu1s = mu1 * mu1, mu2s = mu2 * mu2, mu12 = mu1 * mu2;
    float s1 = acc[2][j] - mu1s, s2 = acc[3][j] - mu2s, s12 = acc[4][j] - mu12;
    float num = (2.f * mu12 + C1) * (2.f * s12 + C2);
    float den = (mu1s + mu2s + C1) * (s1 + s2 + C2);
    int gy = by * TH + yb + j, gx = bx * TW + x;
    out[(size_t)n * IMG * IMG + (size_t)gy * IMG + gx] = num / den;
  }
}

extern "C" void kernel_launch(void* const* d_in, const int* in_sizes, int n_in,
                              void* d_out, int out_size, void* d_ws, size_t ws_size,
                              hipStream_t stream) {
  const float* img1 = (const float*)d_in[0];
  const float* img2 = (const float*)d_in[1];
  float* out = (float*)d_out;
  unsigned* ws = (unsigned*)d_ws;          // [0..1]: final max/min; [16..]: partials
  unsigned* part = ws + 16;
  int n = in_sizes[0];             // 32*1*512*512
  int batch = n / (IMG * IMG);     // 32

  // Gaussian window, center at ws/2 = 5.5 (asymmetric!), normalized
  W11 wv;
  double g[11], s = 0.0;
  for (int i = 0; i < 11; ++i) { double d = i - 5.5; g[i] = exp(-(d * d) / 4.5); s += g[i]; }
  for (int i = 0; i < 11; ++i) wv.w[i] = (float)(g[i] / s);

  minmax_part<<<MMB, 256, 0, stream>>>((const float4*)img1, n / 4, part);
  minmax_final<<<1, 256, 0, stream>>>(part, ws);
  dim3 grid(IMG / TW, IMG / TH, batch);
  ssim_k<<<grid, 256, 0, stream>>>(img1, img2, out, ws, wv);
}

// Round 5
// 179.176 us; speedup vs baseline: 1.2150x; 1.0566x over previous
//
#include <hip/hip_runtime.h>
#include <math.h>

#define IMG 512
#define TW 64      // output tile width
#define TH 16      // output tile height
#define RAD 5
#define IH 26      // h-field rows = TH+10
#define HWP 68     // padded h-field row stride (16B-aligned)
#define NG (IH * (TW / 4))   // 26*16 = 416 horizontal tasks
#define MMB 1024   // minmax stage-1 blocks (4/CU for BW)

struct W11 { float w[11]; };

__device__ __forceinline__ unsigned omap(float f) {
  unsigned b = __float_as_uint(f);
  return (b & 0x80000000u) ? ~b : (b | 0x80000000u);
}
__device__ __forceinline__ float ounmap(unsigned u) {
  return __uint_as_float((u & 0x80000000u) ? (u ^ 0x80000000u) : ~u);
}

// Stage 1: per-block partial min/max -> disjoint slots, no atomics.
__global__ __launch_bounds__(256) void minmax_part(const float4* __restrict__ img,
                                                   int n4, unsigned* __restrict__ part) {
  unsigned mx = 0u, mn = 0xFFFFFFFFu;
  int stride = gridDim.x * blockDim.x;
  for (int i = blockIdx.x * blockDim.x + threadIdx.x; i < n4; i += stride) {
    float4 v = img[i];
    unsigned a = omap(v.x), b = omap(v.y), c = omap(v.z), d = omap(v.w);
    mx = max(mx, max(max(a, b), max(c, d)));
    mn = min(mn, min(min(a, b), min(c, d)));
  }
  #pragma unroll
  for (int off = 32; off > 0; off >>= 1) {
    mx = max(mx, __shfl_down(mx, off));
    mn = min(mn, __shfl_down(mn, off));
  }
  __shared__ unsigned smx[4], smn[4];
  int lane = threadIdx.x & 63, wv = threadIdx.x >> 6;
  if (lane == 0) { smx[wv] = mx; smn[wv] = mn; }
  __syncthreads();
  if (threadIdx.x == 0) {
    mx = max(max(smx[0], smx[1]), max(smx[2], smx[3]));
    mn = min(min(smn[0], smn[1]), min(smn[2], smn[3]));
    part[2 * blockIdx.x]     = mx;
    part[2 * blockIdx.x + 1] = mn;
  }
}

// Stage 2: fold MMB partial pairs into ws[0]=max, ws[1]=min.
__global__ __launch_bounds__(256) void minmax_final(const unsigned* __restrict__ part,
                                                    unsigned* __restrict__ ws) {
  unsigned mx = 0u, mn = 0xFFFFFFFFu;
  for (int i = threadIdx.x; i < MMB; i += 256) {
    mx = max(mx, part[2 * i]);
    mn = min(mn, part[2 * i + 1]);
  }
  #pragma unroll
  for (int off = 32; off > 0; off >>= 1) {
    mx = max(mx, __shfl_down(mx, off));
    mn = min(mn, __shfl_down(mn, off));
  }
  __shared__ unsigned smx[4], smn[4];
  int lane = threadIdx.x & 63, wv = threadIdx.x >> 6;
  if (lane == 0) { smx[wv] = mx; smn[wv] = mn; }
  __syncthreads();
  if (threadIdx.x == 0) {
    ws[0] = max(max(smx[0], smx[1]), max(smx[2], smx[3]));
    ws[1] = min(min(smn[0], smn[1]), min(smn[2], smn[3]));
  }
}

// Fused SSIM: h-pass reads GLOBAL directly (L1 absorbs the 4x overlap; block
// working set ~30KB fits 32KB L1). LDS holds only the 5 h-fields. ONE barrier.
__global__ __launch_bounds__(256, 4) void ssim_k(const float* __restrict__ img1,
                                                 const float* __restrict__ img2,
                                                 float* __restrict__ out,
                                                 const unsigned* __restrict__ ws,
                                                 W11 wv) {
  __shared__ float H[5][IH][HWP];   // h-conv of: x1, x2, x1^2, x2^2, x1*x2 (35.4KB)

  const int tid = threadIdx.x;
  const int bx = blockIdx.x, by = blockIdx.y, n = blockIdx.z;
  const float* p1 = img1 + (size_t)n * IMG * IMG;
  const float* p2 = img2 + (size_t)n * IMG * IMG;
  const int x0 = bx * TW - RAD;     // global x of h-field col 0's first tap
  const int y0 = by * TH - RAD;     // global y of h-field row 0

  const bool x_ok = (bx > 0) & (bx < IMG / TW - 1);
  const bool y_ok = (by > 0) & (by < IMG / TH - 1);

  // ---- horizontal pass: 416 tasks of (1 row, 4 h-cols); direct global reads ----
  #pragma unroll
  for (int it = 0; it < 2; ++it) {
    int g = tid + it * 256;
    if (g < NG) {
      int r = g >> 4;            // h-field row 0..25
      int xg = (g & 15) << 2;    // first of 4 h-field cols (0..60)
      int gy = y0 + r;

      float A20[20], B20[20];
      float* aa = &A20[3];       // aa[t] = input at global x = x0+xg+t
      float* bb = &B20[3];

      bool y_in = y_ok | ((gy >= 0) & (gy < IMG));
      if (!y_in) {
        #pragma unroll
        for (int t = 0; t < 14; ++t) { aa[t] = 0.f; bb[t] = 0.f; }
      } else if (x_ok) {
        // aligned: x0+xg-3 = bx*64 + xg - 8, multiple of 4 -> 16B-aligned f4 loads
        const float* r1 = p1 + gy * IMG + (x0 + xg - 3);
        const float* r2 = p2 + gy * IMG + (x0 + xg - 3);
        #pragma unroll
        for (int m = 0; m < 5; ++m) *(float4*)&A20[4 * m] = *(const float4*)(r1 + 4 * m);
        #pragma unroll
        for (int m = 0; m < 5; ++m) *(float4*)&B20[4 * m] = *(const float4*)(r2 + 4 * m);
      } else {
        const float* r1 = p1 + gy * IMG;
        const float* r2 = p2 + gy * IMG;
        #pragma unroll
        for (int t = 0; t < 14; ++t) {
          int x = x0 + xg + t;
          bool ok = (x >= 0) & (x < IMG);
          aa[t] = ok ? r1[x] : 0.f;
          bb[t] = ok ? r2[x] : 0.f;
        }
      }

      float a2[14], b2[14], ab[14];
      #pragma unroll
      for (int t = 0; t < 14; ++t) {
        a2[t] = aa[t] * aa[t]; b2[t] = bb[t] * bb[t]; ab[t] = aa[t] * bb[t];
      }

      float acc[5][4];
      #pragma unroll
      for (int f = 0; f < 5; ++f)
        #pragma unroll
        for (int j = 0; j < 4; ++j) acc[f][j] = 0.f;

      #pragma unroll
      for (int k = 0; k < 11; ++k) {
        float wk = wv.w[k];
        #pragma unroll
        for (int j = 0; j < 4; ++j) {
          acc[0][j] += wk * aa[j + k];
          acc[1][j] += wk * bb[j + k];
          acc[2][j] += wk * a2[j + k];
          acc[3][j] += wk * b2[j + k];
          acc[4][j] += wk * ab[j + k];
        }
      }
      #pragma unroll
      for (int f = 0; f < 5; ++f)
        *(float4*)&H[f][r][xg] = make_float4(acc[f][0], acc[f][1], acc[f][2], acc[f][3]);
    }
  }
  __syncthreads();   // the only barrier

  // ---- C1/C2 from global min/max ----
  float L = ounmap(ws[0]) - ounmap(ws[1]);
  if (L == 0.f) L = 5.f;
  float C1 = 0.01f * L; C1 *= C1;
  float C2 = 0.03f * L; C2 *= C2;

  // ---- vertical pass: 256 threads = (1 col, 4 rows); full-wave stride-1
  // column reads = 2 lanes/bank = conflict-free ----
  const int x = tid & 63;
  const int yb = (tid >> 6) << 2;
  float acc[5][4];
  #pragma unroll
  for (int f = 0; f < 5; ++f)
    #pragma unroll
    for (int j = 0; j < 4; ++j) acc[f][j] = 0.f;

  #pragma unroll
  for (int f = 0; f < 5; ++f) {
    float v[14];
    #pragma unroll
    for (int i = 0; i < 14; ++i) v[i] = H[f][yb + i][x];
    #pragma unroll
    for (int k = 0; k < 11; ++k) {
      float wk = wv.w[k];
      #pragma unroll
      for (int j = 0; j < 4; ++j) acc[f][j] += wk * v[j + k];
    }
  }

  #pragma unroll
  for (int j = 0; j < 4; ++j) {
    float mu1 = acc[0][j], mu2 = acc[1][j];
    float mu1s = mu1 * mu1, mu2s = mu2 * mu2, mu12 = mu1 * mu2;
    float s1 = acc[2][j] - mu1s, s2 = acc[3][j] - mu2s, s12 = acc[4][j] - mu12;
    float num = (2.f * mu12 + C1) * (2.f * s12 + C2);
    float den = (mu1s + mu2s + C1) * (s1 + s2 + C2);
    int gy = by * TH + yb + j, gx = bx * TW + x;
    out[(size_t)n * IMG * IMG + (size_t)gy * IMG + gx] = num / den;
  }
}

extern "C" void kernel_launch(void* const* d_in, const int* in_sizes, int n_in,
                              void* d_out, int out_size, void* d_ws, size_t ws_size,
                              hipStream_t stream) {
  const float* img1 = (const float*)d_in[0];
  const float* img2 = (const float*)d_in[1];
  float* out = (float*)d_out;
  unsigned* ws = (unsigned*)d_ws;          // [0..1]: final max/min; [16..]: partials
  unsigned* part = ws + 16;
  int n = in_sizes[0];             // 32*1*512*512
  int batch = n / (IMG * IMG);     // 32

  // Gaussian window, center at ws/2 = 5.5 (asymmetric!), normalized
  W11 wv;
  double g[11], s = 0.0;
  for (int i = 0; i < 11; ++i) { double d = i - 5.5; g[i] = exp(-(d * d) / 4.5); s += g[i]; }
  for (int i = 0; i < 11; ++i) wv.w[i] = (float)(g[i] / s);

  minmax_part<<<MMB, 256, 0, stream>>>((const float4*)img1, n / 4, part);
  minmax_final<<<1, 256, 0, stream>>>(part, ws);
  dim3 grid(IMG / TW, IMG / TH, batch);
  ssim_k<<<grid, 256, 0, stream>>>(img1, img2, out, ws, wv);
}

// Round 6
// 178.120 us; speedup vs baseline: 1.2222x; 1.0059x over previous
//
#include <hip/hip_runtime.h>
#include <math.h>

#define IMG 512
#define TW 64      // output tile width
#define TH 16      // output tile height
#define RAD 5
#define IH 26      // h-field rows = TH+10
#define HWP 68     // padded h-field row stride (16B-aligned, 4-bank skew/row)
#define NG (IH * (TW / 4))   // 26*16 = 416 horizontal tasks
#define MMB 1024   // minmax stage-1 blocks

struct W11 { float w[11]; };

__device__ __forceinline__ unsigned omap(float f) {
  unsigned b = __float_as_uint(f);
  return (b & 0x80000000u) ? ~b : (b | 0x80000000u);
}
__device__ __forceinline__ float ounmap(unsigned u) {
  return __uint_as_float((u & 0x80000000u) ? (u ^ 0x80000000u) : ~u);
}

// Stage 1: per-block partial min/max -> disjoint slots, no atomics.
__global__ __launch_bounds__(256) void minmax_part(const float4* __restrict__ img,
                                                   int n4, unsigned* __restrict__ part) {
  unsigned mx = 0u, mn = 0xFFFFFFFFu;
  int stride = gridDim.x * blockDim.x;
  for (int i = blockIdx.x * blockDim.x + threadIdx.x; i < n4; i += stride) {
    float4 v = img[i];
    unsigned a = omap(v.x), b = omap(v.y), c = omap(v.z), d = omap(v.w);
    mx = max(mx, max(max(a, b), max(c, d)));
    mn = min(mn, min(min(a, b), min(c, d)));
  }
  #pragma unroll
  for (int off = 32; off > 0; off >>= 1) {
    mx = max(mx, __shfl_down(mx, off));
    mn = min(mn, __shfl_down(mn, off));
  }
  __shared__ unsigned smx[4], smn[4];
  int lane = threadIdx.x & 63, wv = threadIdx.x >> 6;
  if (lane == 0) { smx[wv] = mx; smn[wv] = mn; }
  __syncthreads();
  if (threadIdx.x == 0) {
    mx = max(max(smx[0], smx[1]), max(smx[2], smx[3]));
    mn = min(min(smn[0], smn[1]), min(smn[2], smn[3]));
    part[2 * blockIdx.x]     = mx;
    part[2 * blockIdx.x + 1] = mn;
  }
}

// Stage 2: fold MMB partial pairs into ws[0]=max, ws[1]=min.
__global__ __launch_bounds__(256) void minmax_final(const unsigned* __restrict__ part,
                                                    unsigned* __restrict__ ws) {
  unsigned mx = 0u, mn = 0xFFFFFFFFu;
  for (int i = threadIdx.x; i < MMB; i += 256) {
    mx = max(mx, part[2 * i]);
    mn = min(mn, part[2 * i + 1]);
  }
  #pragma unroll
  for (int off = 32; off > 0; off >>= 1) {
    mx = max(mx, __shfl_down(mx, off));
    mn = min(mn, __shfl_down(mn, off));
  }
  __shared__ unsigned smx[4], smn[4];
  int lane = threadIdx.x & 63, wv = threadIdx.x >> 6;
  if (lane == 0) { smx[wv] = mx; smn[wv] = mn; }
  __syncthreads();
  if (threadIdx.x == 0) {
    ws[0] = max(max(smx[0], smx[1]), max(smx[2], smx[3]));
    ws[1] = min(min(smn[0], smn[1]), min(smn[2], smn[3]));
  }
}

// Fused SSIM: direct-global h-pass (L1 absorbs 4x overlap), LDS holds only the
// 5 h-fields, one barrier. BS=512: 4 blocks/CU x 8 waves = 32 waves/CU (max),
// doubling latency hiding vs BS=256 (which measured VALUBusy ~50%, occ 27%).
__global__ __launch_bounds__(512, 8) void ssim_k(const float* __restrict__ img1,
                                                 const float* __restrict__ img2,
                                                 float* __restrict__ out,
                                                 const unsigned* __restrict__ ws,
                                                 W11 wv) {
  __shared__ float H[5][IH][HWP];   // h-conv of: x1, x2, x1^2, x2^2, x1*x2 (35.4KB)

  const int tid = threadIdx.x;
  const int bx = blockIdx.x, by = blockIdx.y, n = blockIdx.z;
  const float* p1 = img1 + (size_t)n * IMG * IMG;
  const float* p2 = img2 + (size_t)n * IMG * IMG;
  const int x0 = bx * TW - RAD;
  const int y0 = by * TH - RAD;

  const bool x_ok = (bx > 0) & (bx < IMG / TW - 1);
  const bool y_ok = (by > 0) & (by < IMG / TH - 1);

  // ---- C1/C2 (issue the scalar loads early; result needed after barrier) ----
  float L = ounmap(ws[0]) - ounmap(ws[1]);
  if (L == 0.f) L = 5.f;
  float C1 = 0.01f * L; C1 *= C1;
  float C2 = 0.03f * L; C2 *= C2;

  // ---- horizontal pass: 416 tasks of (1 row, 4 h-cols); one task per thread ----
  if (tid < NG) {
    int r = tid >> 4;            // h-field row 0..25
    int xg = (tid & 15) << 2;    // first of 4 h-field cols (0..60)
    int gy = y0 + r;

    float A20[20], B20[20];
    float* aa = &A20[3];         // aa[t] = input at global x = x0+xg+t
    float* bb = &B20[3];

    bool y_in = y_ok | ((gy >= 0) & (gy < IMG));
    if (!y_in) {
      #pragma unroll
      for (int t = 0; t < 14; ++t) { aa[t] = 0.f; bb[t] = 0.f; }
    } else if (x_ok) {
      // x0+xg-3 = bx*64 + xg - 8 is a multiple of 4 -> 16B-aligned float4 loads
      const float* r1 = p1 + gy * IMG + (x0 + xg - 3);
      const float* r2 = p2 + gy * IMG + (x0 + xg - 3);
      #pragma unroll
      for (int m = 0; m < 5; ++m) *(float4*)&A20[4 * m] = *(const float4*)(r1 + 4 * m);
      #pragma unroll
      for (int m = 0; m < 5; ++m) *(float4*)&B20[4 * m] = *(const float4*)(r2 + 4 * m);
    } else {
      const float* r1 = p1 + gy * IMG;
      const float* r2 = p2 + gy * IMG;
      #pragma unroll
      for (int t = 0; t < 14; ++t) {
        int x = x0 + xg + t;
        bool ok = (x >= 0) & (x < IMG);
        aa[t] = ok ? r1[x] : 0.f;
        bb[t] = ok ? r2[x] : 0.f;
      }
    }

    float a2[14], b2[14], ab[14];
    #pragma unroll
    for (int t = 0; t < 14; ++t) {
      a2[t] = aa[t] * aa[t]; b2[t] = bb[t] * bb[t]; ab[t] = aa[t] * bb[t];
    }

    float acc[5][4];
    #pragma unroll
    for (int f = 0; f < 5; ++f)
      #pragma unroll
      for (int j = 0; j < 4; ++j) acc[f][j] = 0.f;

    #pragma unroll
    for (int k = 0; k < 11; ++k) {
      float wk = wv.w[k];
      #pragma unroll
      for (int j = 0; j < 4; ++j) {
        acc[0][j] += wk * aa[j + k];
        acc[1][j] += wk * bb[j + k];
        acc[2][j] += wk * a2[j + k];
        acc[3][j] += wk * b2[j + k];
        acc[4][j] += wk * ab[j + k];
      }
    }
    #pragma unroll
    for (int f = 0; f < 5; ++f)
      *(float4*)&H[f][r][xg] = make_float4(acc[f][0], acc[f][1], acc[f][2], acc[f][3]);
  }
  __syncthreads();   // the only barrier

  // ---- vertical pass: 512 threads = (1 col, 2 rows); full-wave stride-1
  // column reads = 2 lanes/bank = conflict-free ----
  const int x = tid & 63;
  const int yb = (tid >> 6) << 1;   // 0,2,...,14
  float acc[5][2];
  #pragma unroll
  for (int f = 0; f < 5; ++f) { acc[f][0] = 0.f; acc[f][1] = 0.f; }

  #pragma unroll
  for (int f = 0; f < 5; ++f) {
    float v[12];
    #pragma unroll
    for (int i = 0; i < 12; ++i) v[i] = H[f][yb + i][x];
    #pragma unroll
    for (int k = 0; k < 11; ++k) {
      float wk = wv.w[k];
      acc[f][0] += wk * v[k];
      acc[f][1] += wk * v[k + 1];
    }
  }

  #pragma unroll
  for (int j = 0; j < 2; ++j) {
    float mu1 = acc[0][j], mu2 = acc[1][j];
    float mu1s = mu1 * mu1, mu2s = mu2 * mu2, mu12 = mu1 * mu2;
    float s1 = acc[2][j] - mu1s, s2 = acc[3][j] - mu2s, s12 = acc[4][j] - mu12;
    float num = (2.f * mu12 + C1) * (2.f * s12 + C2);
    float den = (mu1s + mu2s + C1) * (s1 + s2 + C2);
    int gy = by * TH + yb + j, gx = bx * TW + x;
    out[(size_t)n * IMG * IMG + (size_t)gy * IMG + gx] = num / den;
  }
}

extern "C" void kernel_launch(void* const* d_in, const int* in_sizes, int n_in,
                              void* d_out, int out_size, void* d_ws, size_t ws_size,
                              hipStream_t stream) {
  const float* img1 = (const float*)d_in[0];
  const float* img2 = (const float*)d_in[1];
  float* out = (float*)d_out;
  unsigned* ws = (unsigned*)d_ws;          // [0..1]: final max/min; [16..]: partials
  unsigned* part = ws + 16;
  int n = in_sizes[0];             // 32*1*512*512
  int batch = n / (IMG * IMG);     // 32

  // Gaussian window, center at ws/2 = 5.5 (asymmetric!), normalized
  W11 wv;
  double g[11], s = 0.0;
  for (int i = 0; i < 11; ++i) { double d = i - 5.5; g[i] = exp(-(d * d) / 4.5); s += g[i]; }
  for (int i = 0; i < 11; ++i) wv.w[i] = (float)(g[i] / s);

  minmax_part<<<MMB, 256, 0, stream>>>((const float4*)img1, n / 4, part);
  minmax_final<<<1, 256, 0, stream>>>(part, ws);
  dim3 grid(IMG / TW, IMG / TH, batch);
  ssim_k<<<grid, 512, 0, stream>>>(img1, img2, out, ws, wv);
}